// Round 4
// baseline (494.778 us; speedup 1.0000x reference)
//
#include <hip/hip_runtime.h>

// ---------------------------------------------------------------------------
// SelfAttentionPairDim2: B=4, N=256, M=256, D=64, fp32 in/out. bf16 MFMA.
// One workgroup (4 waves) per (b,i). Fused pipeline:
//   QKV proj -> S=relu(K Q^T/8) -> rownorm -> P V -> out proj -> +x -> LN
// Round 4 = round-3 structure + restored write->read __syncthreads() on every
// wave-private LDS staging round-trip (round 3 failed absmax 0.56: cross-lane
// LDS readback without a barrier is a data race the compiler may reorder;
// round 2 passed with barriers, round 3 failed without — only delta).
//  - X A-frags loaded once, reused for Q/K/V^T projections.
//  - K A-frags in registers (stg round-trip, barriered).
//  - Phase 2 ct-outer: Q/V frags shared across 4 mt tiles; 16 independent
//    S-MFMAs + 16 PV-MFMAs per ct.
//  - LDS = 80896 B <= 80 KiB -> 2 blocks/CU.
// ---------------------------------------------------------------------------

using bh8   = __attribute__((ext_vector_type(8))) short;
using f32x4 = __attribute__((ext_vector_type(4))) float;

#define MFMA(a, b, c) __builtin_amdgcn_mfma_f32_16x16x32_bf16((a), (b), (c), 0, 0, 0)

#define SQ_STRIDE  72    // 144 B rows (16B aligned, 2-way bank alias = free)
#define SVT_STRIDE 264   // 528 B rows
#define SP_STRIDE  40    // P stage rows
#define SC_STRIDE  72    // K / ctx stage rows
#define STG_ELTS   1280  // per-wave stage
#define LDS_BYTES  ((256 * SQ_STRIDE + 64 * SVT_STRIDE + 4 * STG_ELTS) * 2)
static_assert(LDS_BYTES <= 81920, "need 2 blocks/CU");

__device__ __forceinline__ unsigned short f2bf(float f) {
  union { float f; unsigned int i; } x;
  x.f = f;
  unsigned int u = x.i + 0x7FFFu + ((x.i >> 16) & 1u);  // RNE
  return (unsigned short)(u >> 16);
}
__device__ __forceinline__ bh8 ld8f(const float* p) {  // 8 fp32 -> bf16x8
  float4 a = *(const float4*)p;
  float4 b = *(const float4*)(p + 4);
  bh8 r;
  r[0] = (short)f2bf(a.x); r[1] = (short)f2bf(a.y);
  r[2] = (short)f2bf(a.z); r[3] = (short)f2bf(a.w);
  r[4] = (short)f2bf(b.x); r[5] = (short)f2bf(b.y);
  r[6] = (short)f2bf(b.z); r[7] = (short)f2bf(b.w);
  return r;
}

__global__ __launch_bounds__(256, 2) void pairattn(
    const float* __restrict__ X,
    const float* __restrict__ Wq, const float* __restrict__ bq,
    const float* __restrict__ Wk, const float* __restrict__ bk,
    const float* __restrict__ Wv, const float* __restrict__ bv,
    const float* __restrict__ Wo, const float* __restrict__ bo,
    const float* __restrict__ lng, const float* __restrict__ lnb,
    float* __restrict__ Out) {
  extern __shared__ unsigned short sm[];
  unsigned short* sQ  = sm;                        // 256 x 72
  unsigned short* sVt = sQ + 256 * SQ_STRIDE;      // 64 x 264 (V transposed)
  unsigned short* sSt = sVt + 64 * SVT_STRIDE;     // 4 x 1280 wave-private

  const int tid  = threadIdx.x;
  const int wv   = tid >> 6;
  const int lane = tid & 63;
  const int q4   = lane >> 4;
  const int l16  = lane & 15;
  const int m0w  = wv << 6;
  const size_t xoff = (size_t)blockIdx.x * 16384;
  unsigned short* stg = sSt + wv * STG_ELTS;

  // ---- X A-fragments, loaded once, reused by all three projections ----
  bh8 xf[4][2];
#pragma unroll
  for (int mt = 0; mt < 4; ++mt) {
    const float* xr = X + xoff + (size_t)(m0w + 16 * mt + l16) * 64 + 8 * q4;
    xf[mt][0] = ld8f(xr);
    xf[mt][1] = ld8f(xr + 32);
  }

  // ---- Q projection -> sQ (block-wide) ----
  {
    bh8 wf[4][2];
    float bsf[4];
#pragma unroll
    for (int nt = 0; nt < 4; ++nt) {
      const float* wr = Wq + (16 * nt + l16) * 64 + 8 * q4;
      wf[nt][0] = ld8f(wr);
      wf[nt][1] = ld8f(wr + 32);
      bsf[nt]   = bq[16 * nt + l16];
    }
#pragma unroll
    for (int mt = 0; mt < 4; ++mt)
#pragma unroll
      for (int nt = 0; nt < 4; ++nt) {
        f32x4 acc = {0.f, 0.f, 0.f, 0.f};
        acc = MFMA(xf[mt][0], wf[nt][0], acc);
        acc = MFMA(xf[mt][1], wf[nt][1], acc);
#pragma unroll
        for (int r = 0; r < 4; ++r)
          sQ[(m0w + 16 * mt + 4 * q4 + r) * SQ_STRIDE + 16 * nt + l16] =
              f2bf(acc[r] + bsf[nt]);
      }
  }

  // ---- V^T projection -> sVt (block-wide) ----
  {
    bh8 wf[4][2];
    float bvf[4][4];
#pragma unroll
    for (int dt = 0; dt < 4; ++dt) {
      const float* wr = Wv + (16 * dt + l16) * 64 + 8 * q4;
      wf[dt][0] = ld8f(wr);
      wf[dt][1] = ld8f(wr + 32);
#pragma unroll
      for (int r = 0; r < 4; ++r) bvf[dt][r] = bv[16 * dt + 4 * q4 + r];
    }
#pragma unroll
    for (int mt = 0; mt < 4; ++mt)
#pragma unroll
      for (int dt = 0; dt < 4; ++dt) {
        f32x4 acc = {0.f, 0.f, 0.f, 0.f};
        acc = MFMA(wf[dt][0], xf[mt][0], acc);
        acc = MFMA(wf[dt][1], xf[mt][1], acc);
#pragma unroll
        for (int r = 0; r < 4; ++r)
          sVt[(16 * dt + 4 * q4 + r) * SVT_STRIDE + m0w + 16 * mt + l16] =
              f2bf(acc[r] + bvf[dt][r]);
      }
  }

  // ---- K projection -> REGISTERS (stg round-trip, write->read barriered) ----
  bh8 kf[4][2];
  {
    bh8 wf[4][2];
    float bsf[4];
#pragma unroll
    for (int nt = 0; nt < 4; ++nt) {
      const float* wr = Wk + (16 * nt + l16) * 64 + 8 * q4;
      wf[nt][0] = ld8f(wr);
      wf[nt][1] = ld8f(wr + 32);
      bsf[nt]   = bk[16 * nt + l16];
    }
#pragma unroll 1
    for (int mt = 0; mt < 4; ++mt) {
#pragma unroll
      for (int nt = 0; nt < 4; ++nt) {
        f32x4 acc = {0.f, 0.f, 0.f, 0.f};
        acc = MFMA(xf[mt][0], wf[nt][0], acc);
        acc = MFMA(xf[mt][1], wf[nt][1], acc);
#pragma unroll
        for (int r = 0; r < 4; ++r)
          stg[(4 * q4 + r) * SC_STRIDE + 16 * nt + l16] = f2bf(acc[r] + bsf[nt]);
      }
      __syncthreads();  // write->read (cross-lane LDS needs a real barrier)
      kf[mt][0] = *(const bh8*)(stg + l16 * SC_STRIDE + 8 * q4);
      kf[mt][1] = *(const bh8*)(stg + l16 * SC_STRIDE + 8 * q4 + 32);
    }
  }
  __syncthreads();  // sQ/sVt valid block-wide; also WAR-protects last K stage

  // ---- Phase 2: ct-outer fused S -> P -> PV ----
  f32x4 ctxa[4][4];  // [mt][dt]
  float rs[4][4];    // [mt][r]
#pragma unroll
  for (int mt = 0; mt < 4; ++mt) {
#pragma unroll
    for (int dt = 0; dt < 4; ++dt) ctxa[mt][dt] = (f32x4){0.f, 0.f, 0.f, 0.f};
#pragma unroll
    for (int r = 0; r < 4; ++r) rs[mt][r] = 0.f;
  }

#pragma unroll 1
  for (int ct = 0; ct < 8; ++ct) {
    const unsigned short* qrow = sQ + (32 * ct + l16) * SQ_STRIDE + 8 * q4;
    bh8 qa0 = *(const bh8*)(qrow);
    bh8 qa1 = *(const bh8*)(qrow + 32);
    bh8 qb0 = *(const bh8*)(qrow + 16 * SQ_STRIDE);
    bh8 qb1 = *(const bh8*)(qrow + 16 * SQ_STRIDE + 32);
    bh8 vf[4];
#pragma unroll
    for (int dt = 0; dt < 4; ++dt)
      vf[dt] = *(const bh8*)(sVt + (16 * dt + l16) * SVT_STRIDE + 32 * ct + 8 * q4);

    f32x4 sA[4], sB[4];  // 16 independent MFMAs
#pragma unroll
    for (int mt = 0; mt < 4; ++mt) {
      f32x4 z = {0.f, 0.f, 0.f, 0.f};
      sA[mt] = MFMA(kf[mt][0], qa0, z);
      sA[mt] = MFMA(kf[mt][1], qa1, sA[mt]);
      sB[mt] = MFMA(kf[mt][0], qb0, z);
      sB[mt] = MFMA(kf[mt][1], qb1, sB[mt]);
    }

#pragma unroll
    for (int half = 0; half < 2; ++half) {
#pragma unroll
      for (int i = 0; i < 2; ++i) {
        const int m = 2 * half + i;
#pragma unroll
        for (int r = 0; r < 4; ++r) {
          float v0 = fmaxf(sA[m][r] * 0.125f, 0.f);
          float v1 = fmaxf(sB[m][r] * 0.125f, 0.f);
          rs[m][r] += v0 + v1;
          stg[i * 640 + (4 * q4 + r) * SP_STRIDE + l16]      = f2bf(v0);
          stg[i * 640 + (4 * q4 + r) * SP_STRIDE + 16 + l16] = f2bf(v1);
        }
      }
      __syncthreads();  // write->read for the P stage
#pragma unroll
      for (int i = 0; i < 2; ++i) {
        const int m = 2 * half + i;
        bh8 pf = *(const bh8*)(stg + i * 640 + l16 * SP_STRIDE + 8 * q4);
#pragma unroll
        for (int dt = 0; dt < 4; ++dt)
          ctxa[m][dt] = MFMA(pf, vf[dt], ctxa[m][dt]);
      }
    }
  }

  // ---- Epilogue: rownorm scale, out proj, residual, LayerNorm ----
  bh8 wof[4][2];
  float bof[4], gf[4], lbf[4];
#pragma unroll
  for (int nt = 0; nt < 4; ++nt) {
    const float* wr = Wo + (16 * nt + l16) * 64 + 8 * q4;
    wof[nt][0] = ld8f(wr);
    wof[nt][1] = ld8f(wr + 32);
    const int col = 16 * nt + l16;
    bof[nt] = bo[col];
    gf[nt]  = lng[col];
    lbf[nt] = lnb[col];
  }

#pragma unroll 1
  for (int mt = 0; mt < 4; ++mt) {
    const int a0 = m0w + 16 * mt;
    // denom = sum_c relu + M*1e-12 (reference sums probs + 1e-12)
#pragma unroll
    for (int r = 0; r < 4; ++r) {
      float t = rs[mt][r];
      t += __shfl_xor(t, 1);
      t += __shfl_xor(t, 2);
      t += __shfl_xor(t, 4);
      t += __shfl_xor(t, 8);
      const float inv = 1.f / (t + 2.56e-10f);
#pragma unroll
      for (int dt = 0; dt < 4; ++dt)
        stg[(4 * q4 + r) * SC_STRIDE + 16 * dt + l16] =
            f2bf(ctxa[mt][dt][r] * inv);
    }
    __syncthreads();  // write->read for the ctx stage
    const unsigned short* crow = stg + l16 * SC_STRIDE + 8 * q4;
    bh8 cf0 = *(const bh8*)(crow);
    bh8 cf1 = *(const bh8*)(crow + 32);

    float yv[4][4];
    float s1[4] = {0.f, 0.f, 0.f, 0.f};
    float s2[4] = {0.f, 0.f, 0.f, 0.f};
#pragma unroll
    for (int nt = 0; nt < 4; ++nt) {
      f32x4 o = {0.f, 0.f, 0.f, 0.f};
      o = MFMA(cf0, wof[nt][0], o);
      o = MFMA(cf1, wof[nt][1], o);
#pragma unroll
      for (int r = 0; r < 4; ++r) {
        float y = o[r] + bof[nt] +
                  X[xoff + (size_t)(a0 + 4 * q4 + r) * 64 + 16 * nt + l16];
        yv[nt][r] = y;
        s1[r] += y;
        s2[r] += y * y;
      }
    }
#pragma unroll
    for (int r = 0; r < 4; ++r) {
      s1[r] += __shfl_xor(s1[r], 1);
      s1[r] += __shfl_xor(s1[r], 2);
      s1[r] += __shfl_xor(s1[r], 4);
      s1[r] += __shfl_xor(s1[r], 8);
      s2[r] += __shfl_xor(s2[r], 1);
      s2[r] += __shfl_xor(s2[r], 2);
      s2[r] += __shfl_xor(s2[r], 4);
      s2[r] += __shfl_xor(s2[r], 8);
      const float mu   = s1[r] * 0.015625f;
      const float var  = s2[r] * 0.015625f - mu * mu;
      const float rstd = rsqrtf(var + 1e-5f);
#pragma unroll
      for (int nt = 0; nt < 4; ++nt)
        Out[xoff + (size_t)(a0 + 4 * q4 + r) * 64 + 16 * nt + l16] =
            (yv[nt][r] - mu) * rstd * gf[nt] + lbf[nt];
    }
  }
}

extern "C" void kernel_launch(void* const* d_in, const int* in_sizes, int n_in,
                              void* d_out, int out_size, void* d_ws, size_t ws_size,
                              hipStream_t stream) {
  (void)in_sizes; (void)n_in; (void)d_ws; (void)ws_size; (void)out_size;
  const float* X  = (const float*)d_in[1];  // d_in[0]=hidden_states unused
  const float* Wq = (const float*)d_in[2];  const float* bq = (const float*)d_in[3];
  const float* Wk = (const float*)d_in[4];  const float* bk = (const float*)d_in[5];
  const float* Wv = (const float*)d_in[6];  const float* bv = (const float*)d_in[7];
  const float* Wo = (const float*)d_in[8];  const float* bo = (const float*)d_in[9];
  const float* lg = (const float*)d_in[10]; const float* lb = (const float*)d_in[11];

  hipFuncSetAttribute((const void*)pairattn,
                      hipFuncAttributeMaxDynamicSharedMemorySize, LDS_BYTES);
  pairattn<<<1024, 256, LDS_BYTES, stream>>>(X, Wq, bq, Wk, bk, Wv, bv, Wo, bo,
                                             lg, lb, (float*)d_out);
}

// Round 6
// 282.176 us; speedup vs baseline: 1.7534x; 1.7534x over previous
//
#include <hip/hip_runtime.h>

// ---------------------------------------------------------------------------
// SelfAttentionPairDim2: B=4, N=256, M=256, D=64, fp32 in/out. bf16 MFMA.
// One workgroup (4 waves) per (b,i). Fused:
//   QKV proj -> S=relu(K Q^T/8) -> rownorm -> P V -> out proj -> +x -> LN
// Round 6: NO cross-lane LDS round-trips in hot paths. All C-layout -> A/B-
// layout transforms go through __shfl (ds_bpermute register dataflow, race-
// free by construction):
//  - S computed TRANSPOSED (S^T = Q K^T, A=Q rows, B=kf regs) so the a-index
//    stays lane-resident (a = lane&15); P A/B-frag built with 16 shuffles
//    per 32-col block.
//  - ctx computed TRANSPOSED (ctx^T = V^T P^T) so inv[a] is lane-resident;
//    out-proj A-frag built with 32 shuffles per mt tile.
//  - K (needs a full transpose) staged through the sQ region BEFORE Q lives
//    there: K-proj -> sQ region, B1, kf reads, B2, Q-proj -> sQ, V^T -> sVt,
//    B3 (publish). THREE __syncthreads total, all phase 1, none in loops.
//  - mt-outer phase 2 (round 4's ct-outer spilled: 399 MB scratch writes).
//  - LDS = 70656 B -> 2 blocks/CU.
// ---------------------------------------------------------------------------

using bh8   = __attribute__((ext_vector_type(8))) short;
using f32x4 = __attribute__((ext_vector_type(4))) float;

#define MFMA(a, b, c) __builtin_amdgcn_mfma_f32_16x16x32_bf16((a), (b), (c), 0, 0, 0)

#define SQ_STRIDE  72    // 144 B rows (16B aligned; 2-way bank alias = free)
#define SVT_STRIDE 264   // 528 B rows
#define LDS_BYTES  ((256 * SQ_STRIDE + 64 * SVT_STRIDE) * 2)  // 70656 B
static_assert(LDS_BYTES <= 81920, "need 2 blocks/CU");

__device__ __forceinline__ unsigned short f2bf(float f) {
  union { float f; unsigned int i; } x;
  x.f = f;
  unsigned int u = x.i + 0x7FFFu + ((x.i >> 16) & 1u);  // RNE
  return (unsigned short)(u >> 16);
}
__device__ __forceinline__ bh8 ld8f(const float* p) {  // 8 fp32 -> bf16x8
  float4 a = *(const float4*)p;
  float4 b = *(const float4*)(p + 4);
  bh8 r;
  r[0] = (short)f2bf(a.x); r[1] = (short)f2bf(a.y);
  r[2] = (short)f2bf(a.z); r[3] = (short)f2bf(a.w);
  r[4] = (short)f2bf(b.x); r[5] = (short)f2bf(b.y);
  r[6] = (short)f2bf(b.z); r[7] = (short)f2bf(b.w);
  return r;
}

__global__ __launch_bounds__(256, 2) void pairattn(
    const float* __restrict__ X,
    const float* __restrict__ Wq, const float* __restrict__ bq,
    const float* __restrict__ Wk, const float* __restrict__ bk,
    const float* __restrict__ Wv, const float* __restrict__ bv,
    const float* __restrict__ Wo, const float* __restrict__ bo,
    const float* __restrict__ lng, const float* __restrict__ lnb,
    float* __restrict__ Out) {
  extern __shared__ unsigned short sm[];
  unsigned short* sQ  = sm;                    // 256 x 72 (first holds K!)
  unsigned short* sVt = sQ + 256 * SQ_STRIDE;  // 64 x 264 (V transposed)

  const int tid  = threadIdx.x;
  const int wv   = tid >> 6;
  const int lane = tid & 63;
  const int q4   = lane >> 4;
  const int l16  = lane & 15;
  const int m0w  = wv << 6;
  const size_t xoff = (size_t)blockIdx.x * 16384;
  // shuffle source base: lane (2*(q4&1))*16 + l16  (+16 for jj=1)
  const int sbase = ((lane & 16) << 1) | l16;

  // ---- X A-fragments, loaded once, reused by all three projections ----
  bh8 xf[4][2];
#pragma unroll
  for (int mt = 0; mt < 4; ++mt) {
    const float* xr = X + xoff + (size_t)(m0w + 16 * mt + l16) * 64 + 8 * q4;
    xf[mt][0] = ld8f(xr);
    xf[mt][1] = ld8f(xr + 32);
  }

  // ---- K projection -> sQ region (temporarily), standard [a][d] layout ----
  {
    bh8 wf[4][2];
    float bsf[4];
#pragma unroll
    for (int nt = 0; nt < 4; ++nt) {
      const float* wr = Wk + (16 * nt + l16) * 64 + 8 * q4;
      wf[nt][0] = ld8f(wr);
      wf[nt][1] = ld8f(wr + 32);
      bsf[nt]   = bk[16 * nt + l16];
    }
#pragma unroll
    for (int mt = 0; mt < 4; ++mt)
#pragma unroll
      for (int nt = 0; nt < 4; ++nt) {
        f32x4 acc = {0.f, 0.f, 0.f, 0.f};
        acc = MFMA(xf[mt][0], wf[nt][0], acc);
        acc = MFMA(xf[mt][1], wf[nt][1], acc);
#pragma unroll
        for (int r = 0; r < 4; ++r)
          sQ[(m0w + 16 * mt + 4 * q4 + r) * SQ_STRIDE + 16 * nt + l16] =
              f2bf(acc[r] + bsf[nt]);
      }
  }
  __syncthreads();  // B1: K rows committed

  // kf[mt] = K[a = m0w+16mt+l16][d = 8q4+j (+32h)]  (A/B-frag layout)
  bh8 kf[4][2];
#pragma unroll
  for (int mt = 0; mt < 4; ++mt) {
    const unsigned short* kr = sQ + (m0w + 16 * mt + l16) * SQ_STRIDE + 8 * q4;
    kf[mt][0] = *(const bh8*)(kr);
    kf[mt][1] = *(const bh8*)(kr + 32);
  }
  __syncthreads();  // B2: kf reads done; sQ region free for Q

  // ---- Q projection -> sQ ----
  {
    bh8 wf[4][2];
    float bsf[4];
#pragma unroll
    for (int nt = 0; nt < 4; ++nt) {
      const float* wr = Wq + (16 * nt + l16) * 64 + 8 * q4;
      wf[nt][0] = ld8f(wr);
      wf[nt][1] = ld8f(wr + 32);
      bsf[nt]   = bq[16 * nt + l16];
    }
#pragma unroll
    for (int mt = 0; mt < 4; ++mt)
#pragma unroll
      for (int nt = 0; nt < 4; ++nt) {
        f32x4 acc = {0.f, 0.f, 0.f, 0.f};
        acc = MFMA(xf[mt][0], wf[nt][0], acc);
        acc = MFMA(xf[mt][1], wf[nt][1], acc);
#pragma unroll
        for (int r = 0; r < 4; ++r)
          sQ[(m0w + 16 * mt + 4 * q4 + r) * SQ_STRIDE + 16 * nt + l16] =
              f2bf(acc[r] + bsf[nt]);
      }
  }

  // ---- V^T projection -> sVt ----
  {
    bh8 wf[4][2];
    float bvf[4][4];
#pragma unroll
    for (int dt = 0; dt < 4; ++dt) {
      const float* wr = Wv + (16 * dt + l16) * 64 + 8 * q4;
      wf[dt][0] = ld8f(wr);
      wf[dt][1] = ld8f(wr + 32);
#pragma unroll
      for (int r = 0; r < 4; ++r) bvf[dt][r] = bv[16 * dt + 4 * q4 + r];
    }
#pragma unroll
    for (int mt = 0; mt < 4; ++mt)
#pragma unroll
      for (int dt = 0; dt < 4; ++dt) {
        f32x4 acc = {0.f, 0.f, 0.f, 0.f};
        acc = MFMA(wf[dt][0], xf[mt][0], acc);
        acc = MFMA(wf[dt][1], xf[mt][1], acc);
#pragma unroll
        for (int r = 0; r < 4; ++r)
          sVt[(16 * dt + 4 * q4 + r) * SVT_STRIDE + m0w + 16 * mt + l16] =
              f2bf(acc[r] + bvf[dt][r]);
      }
  }
  __syncthreads();  // B3: sQ/sVt published. Last barrier.

  // ---- Epilogue constants ----
  bh8 wof[4][2];
  float bof[4], gf[4], lbf[4];
#pragma unroll
  for (int nt = 0; nt < 4; ++nt) {
    const float* wr = Wo + (16 * nt + l16) * 64 + 8 * q4;
    wof[nt][0] = ld8f(wr);
    wof[nt][1] = ld8f(wr + 32);
    const int col = 16 * nt + l16;
    bof[nt] = bo[col];
    gf[nt]  = lng[col];
    lbf[nt] = lnb[col];
  }

  // ---- Phase 2: mt-outer, barrier-free (shuffle-based transforms) ----
#pragma unroll 1
  for (int mt = 0; mt < 4; ++mt) {
    const int a0 = m0w + 16 * mt;  // tile rows; lane-resident a = a0 + l16
    f32x4 ctxa[4];                 // ctx^T[16dt+4q4+r][a0+l16]
#pragma unroll
    for (int dt = 0; dt < 4; ++dt) ctxa[dt] = (f32x4){0.f, 0.f, 0.f, 0.f};
    float rs = 0.f;  // sum_c relu for a = a0+l16 (partial over q4 share)

#pragma unroll 1
    for (int blk = 0; blk < 8; ++blk) {  // 32 c-columns per iteration
      const unsigned short* qr = sQ + (32 * blk + l16) * SQ_STRIDE + 8 * q4;
      bh8 qa0 = *(const bh8*)(qr);
      bh8 qa1 = *(const bh8*)(qr + 32);
      bh8 qb0 = *(const bh8*)(qr + 16 * SQ_STRIDE);
      bh8 qb1 = *(const bh8*)(qr + 16 * SQ_STRIDE + 32);

      // S^T chunks: st[r] = S^T[c = 32blk(+16) + 4q4 + r][a0 + l16]
      f32x4 z = {0.f, 0.f, 0.f, 0.f};
      f32x4 stA = MFMA(qa0, kf[mt][0], z);
      stA = MFMA(qa1, kf[mt][1], stA);
      f32x4 stB = MFMA(qb0, kf[mt][0], z);
      stB = MFMA(qb1, kf[mt][1], stB);

      float pA[4], pB[4];
#pragma unroll
      for (int r = 0; r < 4; ++r) {
        pA[r] = fmaxf(stA[r] * 0.125f, 0.f);  // relu(scores/sqrt(64))
        pB[r] = fmaxf(stB[r] * 0.125f, 0.f);
        rs += pA[r] + pB[r];
      }

      // Build pf = P[a = a0+l16][c_rel = 8q4+j] via register shuffles.
      // src lane = (2*(q4&1) + jj)*16 + l16 ; chunk select by q4>>1.
      bh8 pf;
#pragma unroll
      for (int jj = 0; jj < 2; ++jj) {
        const int src = sbase + (jj << 4);
#pragma unroll
        for (int r = 0; r < 4; ++r) {
          float vA = __shfl(pA[r], src);
          float vB = __shfl(pB[r], src);
          pf[jj * 4 + r] = (short)f2bf(q4 < 2 ? vA : vB);
        }
      }

      // ctx^T += V^T-frag (A) x P^T-frag (B)
#pragma unroll
      for (int dt = 0; dt < 4; ++dt) {
        bh8 vf = *(const bh8*)(sVt + (16 * dt + l16) * SVT_STRIDE + 32 * blk + 8 * q4);
        ctxa[dt] = MFMA(vf, pf, ctxa[dt]);
      }
    }

    // denom[a=l16]: finish sum over q4 groups; reference: sum(p + 1e-12)
    rs += __shfl_xor(rs, 16);
    rs += __shfl_xor(rs, 32);
    const float inv = 1.f / (rs + 2.56e-10f);

    // Out-proj A-frag: af[h][j] = ctx_scaled[a=l16][dv = 8q4+j+32h] via shfl
    bh8 af0, af1;
#pragma unroll
    for (int jj = 0; jj < 2; ++jj) {
      const int src = sbase + (jj << 4);
#pragma unroll
      for (int r = 0; r < 4; ++r) {
        float t0 = __shfl(ctxa[0][r] * inv, src);
        float t1 = __shfl(ctxa[1][r] * inv, src);
        float t2 = __shfl(ctxa[2][r] * inv, src);
        float t3 = __shfl(ctxa[3][r] * inv, src);
        af0[jj * 4 + r] = (short)f2bf(q4 < 2 ? t0 : t1);
        af1[jj * 4 + r] = (short)f2bf(q4 < 2 ? t2 : t3);
      }
    }

    // out proj -> residual -> LayerNorm -> store (rows a = a0+4q4+r)
    float yv[4][4];
    float s1[4] = {0.f, 0.f, 0.f, 0.f};
    float s2[4] = {0.f, 0.f, 0.f, 0.f};
#pragma unroll
    for (int nt = 0; nt < 4; ++nt) {
      f32x4 o = {0.f, 0.f, 0.f, 0.f};
      o = MFMA(af0, wof[nt][0], o);
      o = MFMA(af1, wof[nt][1], o);
#pragma unroll
      for (int r = 0; r < 4; ++r) {
        float y = o[r] + bof[nt] +
                  X[xoff + (size_t)(a0 + 4 * q4 + r) * 64 + 16 * nt + l16];
        yv[nt][r] = y;
        s1[r] += y;
        s2[r] += y * y;
      }
    }
#pragma unroll
    for (int r = 0; r < 4; ++r) {
      s1[r] += __shfl_xor(s1[r], 1);
      s1[r] += __shfl_xor(s1[r], 2);
      s1[r] += __shfl_xor(s1[r], 4);
      s1[r] += __shfl_xor(s1[r], 8);
      s2[r] += __shfl_xor(s2[r], 1);
      s2[r] += __shfl_xor(s2[r], 2);
      s2[r] += __shfl_xor(s2[r], 4);
      s2[r] += __shfl_xor(s2[r], 8);
      const float mu   = s1[r] * 0.015625f;
      const float var  = s2[r] * 0.015625f - mu * mu;
      const float rstd = rsqrtf(var + 1e-5f);
#pragma unroll
      for (int nt = 0; nt < 4; ++nt)
        Out[xoff + (size_t)(a0 + 4 * q4 + r) * 64 + 16 * nt + l16] =
            (yv[nt][r] - mu) * rstd * gf[nt] + lbf[nt];
    }
  }
}

extern "C" void kernel_launch(void* const* d_in, const int* in_sizes, int n_in,
                              void* d_out, int out_size, void* d_ws, size_t ws_size,
                              hipStream_t stream) {
  (void)in_sizes; (void)n_in; (void)d_ws; (void)ws_size; (void)out_size;
  const float* X  = (const float*)d_in[1];  // d_in[0]=hidden_states unused
  const float* Wq = (const float*)d_in[2];  const float* bq = (const float*)d_in[3];
  const float* Wk = (const float*)d_in[4];  const float* bk = (const float*)d_in[5];
  const float* Wv = (const float*)d_in[6];  const float* bv = (const float*)d_in[7];
  const float* Wo = (const float*)d_in[8];  const float* bo = (const float*)d_in[9];
  const float* lg = (const float*)d_in[10]; const float* lb = (const float*)d_in[11];

  hipFuncSetAttribute((const void*)pairattn,
                      hipFuncAttributeMaxDynamicSharedMemorySize, LDS_BYTES);
  pairattn<<<1024, 256, LDS_BYTES, stream>>>(X, Wq, bq, Wk, bk, Wv, bv, Wo, bo,
                                             lg, lb, (float*)d_out);
}